// Round 7
// baseline (1046.834 us; speedup 1.0000x reference)
//
#include <hip/hip_runtime.h>
#include <math.h>

#define Bv 8
#define Nv 2048
#define DIMv 1024
#define Hv 16
#define Dv 64
#define Rv 5
#define RMv 10

// output layout (flat concat, fp32)
#define ATTN_OFF 0
#define ESC_OFF (Bv * Nv * DIMv)              // 16777216
#define RSC_OFF (ESC_OFF + Bv * Hv * Nv * Rv) // 18087936
#define KL_OFF  (RSC_OFF + Bv * Hv * Nv * Rv) // 19398656

#define BMt 128      // rows per block
#define BK 64        // fp16 k-chunk per phase (full 128B cache lines per row)

#define XHALFS (Bv * Nv * DIMv)     // 16777216
#define QKHALFS (2 * DIMv * DIMv)   // 2097152
#define CONV_BLOCKS ((XHALFS + QKHALFS) / 8 / 256)   // 9216

using half8 = __attribute__((ext_vector_type(8))) _Float16;
using f32x4 = __attribute__((ext_vector_type(4))) float;

#define GLOAD(gp, lp)                                                      \
    __builtin_amdgcn_global_load_lds(                                      \
        (const __attribute__((address_space(1))) void*)(gp),               \
        (__attribute__((address_space(3))) void*)(lp), 16, 0, 0)

// ---- pre-pass: fp32 -> fp16 of x and qk_w into workspace; last block does KL
__global__ __launch_bounds__(256)
void convert_fp16(const float* __restrict__ x, const float* __restrict__ qk,
                  _Float16* __restrict__ xh, _Float16* __restrict__ qkh,
                  const float* __restrict__ log_lam, const float* __restrict__ m_u,
                  const float* __restrict__ s_tri, const float* __restrict__ log_ssqrt,
                  float* __restrict__ out)
{
    __shared__ float red[256];
    const int t = threadIdx.x;

    if (blockIdx.x == CONV_BLOCKS) {
        // ---- KL reduction (single block)
        float acc = 0.f;
        for (int idx = t; idx < Hv * Rv * Rv * Rv; idx += 256) {
            int hh = idx / 125;
            int rem = idx % 125;
            int a = rem / 25, u = (rem / 5) % 5, c = rem % 5;
            float S = 0.f;
            if (u == c)      S = expf(log_ssqrt[(hh * Rv + a) * Rv + u]);
            else if (u > c)  S = s_tri[((hh * Rv + a) * Rv + u) * Rv + c];
            float lam2 = expf(2.f * log_lam[hh * Rv + a]);
            float z = lam2 * S;
            acc += 0.5f * z * z;
        }
        for (int idx = t; idx < Hv * Rv * Rv; idx += 256) {
            int hh = idx / 25, a = (idx / 5) % 5;
            float e4 = expf(4.f * log_lam[hh * Rv + a]);
            float mu = m_u[idx];
            acc += 0.5f * e4 * mu * mu;
            acc -= log_ssqrt[idx];
        }
        for (int idx = t; idx < Hv * Rv; idx += 256) acc -= 2.f * (float)Rv * log_lam[idx];

        red[t] = acc;
        __syncthreads();
        for (int s = 128; s > 0; s >>= 1) {
            if (t < s) red[t] += red[t + s];
            __syncthreads();
        }
        if (t == 0) out[KL_OFF] = red[0] - 0.5f * (float)(Rv * Rv * Hv);
        return;
    }

    size_t i = ((size_t)blockIdx.x * 256 + t) * 8;
    const float* src;
    _Float16* dst;
    if (i < XHALFS) { src = x + i; dst = xh + i; }
    else            { src = qk + (i - XHALFS); dst = qkh + (i - XHALFS); }
    float4 v0 = *(const float4*)src;
    float4 v1 = *(const float4*)(src + 4);
    half8 hv = {(_Float16)v0.x, (_Float16)v0.y, (_Float16)v0.z, (_Float16)v0.w,
                (_Float16)v1.x, (_Float16)v1.y, (_Float16)v1.z, (_Float16)v1.w};
    *(half8*)dst = hv;
}

// grid: 2048 1-D (xcd-affine: id&7 -> heads {2x,2x+1}); block: 256 = 4 waves
// single-buffer m97-style schedule; 37.4KB LDS -> 4 blocks/CU (16 waves/CU):
// cross-block wave overlap hides staging latency (m114 mechanism).
__global__ __launch_bounds__(256, 4)
void svgp_main(const _Float16* __restrict__ xh, const _Float16* __restrict__ qkh,
               const float* __restrict__ x, const float* __restrict__ mask,
               const float* __restrict__ eps,
               const float* __restrict__ we_p, const float* __restrict__ wr_p,
               const float* __restrict__ log_lam, const float* __restrict__ m_u,
               const float* __restrict__ s_tri, const float* __restrict__ log_ssqrt,
               const float* __restrict__ fw_w, const float* __restrict__ fw_b,
               float* __restrict__ out)
{
    const int id = blockIdx.x;
    const int h = 2 * (id & 7) + ((id >> 3) & 1);
    const int rowTile = id >> 4;           // 0..127
    const int row0 = rowTile * BMt;        // flat row base (b*N + n)
    const int b0 = row0 >> 11;             // batch (tile never straddles b)
    const int t = threadIdx.x;
    const int lane = t & 63;
    const int w = t >> 6;
    const int wu = __builtin_amdgcn_readfirstlane(w);   // wave-uniform
    const int dm = lane & 15;
    const int rg = lane >> 4;

    // LDS: single staging buffer A 16KB + B 16KB; aliased (post K-loop) with sRed
    __shared__ float4 sStageV[2048];       // 32 KB
    char* sBytes = (char*)sStageV;
    float (*sRed)[12] = (float (*)[12])sStageV;

    __shared__ float sS[Rv][Rv][Rv];
    __shared__ float sMu[Rv][Rv];
    __shared__ float sFw[Dv][Rv];
    __shared__ float sFb[Dv];
    __shared__ float sLam2[Rv];
    __shared__ float sWe[Dv][Rv];
    __shared__ float sWr[Dv][Rv];

    // ---- small tables (reads happen only after K-loop barriers)
    if (t < 125) {
        int a = t / 25, u = (t % 25) / 5, c = t % 5;
        float v = 0.f;
        if (u == c)      v = expf(log_ssqrt[(h * Rv + a) * Rv + u]);
        else if (u > c)  v = s_tri[((h * Rv + a) * Rv + u) * Rv + c];
        sS[a][u][c] = v;
    }
    if (t >= 128 && t < 153) { int i = t - 128; sMu[i / 5][i % 5] = m_u[h * Rv * Rv + i]; }
    if (t >= 160 && t < 165) sLam2[t - 160] = expf(2.f * log_lam[h * Rv + (t - 160)]);
    if (t >= 192 && t < 256) sFb[t - 192] = fw_b[t - 192];
    if (t < 320) sFw[t / Rv][t % Rv] = fw_w[t];
    { int t2 = t + 256; if (t2 < 320) sFw[t2 / Rv][t2 % Rv] = fw_w[t2]; }

    // ---- we/wr once per block (wave 0, lane = d), fp32
    if (t < 64) {
        float xv[RMv];
#pragma unroll
        for (int m = 0; m < RMv; ++m) {
            int nidx = (m == RMv - 1) ? (Nv - 1) : (int)((float)m * (2047.0f / 9.0f));
            xv[m] = x[((size_t)b0 * Nv + nidx) * DIMv + h * Dv + t];
        }
#pragma unroll
        for (int rr = 0; rr < Rv; ++rr) {
            float sw = 0.f, sr = 0.f;
#pragma unroll
            for (int m = 0; m < RMv; ++m) {
                sw = fmaf(xv[m], we_p[(h * RMv + m) * Rv + rr], sw);
                sr = fmaf(xv[m], wr_p[(h * RMv + m) * Rv + rr], sr);
            }
            sWe[t][rr] = sw; sWr[t][rr] = sr;
        }
    }

    // ---- staging address precompute (k0-invariant), BK=64 full-line phases
    // slot s = c*64 + lane; rl = (s>>7)*16 + (s&15); ko = (s>>4)&7
    // LDS fragment-major: slot = mtile*128 + ko*16 + mrow, 8 halfs (16B) per slot
    size_t aOff[4], bOff[4];
    int ldsA[4], ldsB[4];
#pragma unroll
    for (int j = 0; j < 4; ++j) {
        int c = wu * 4 + j;
        int s = c * 64 + lane;
        int rl = ((s >> 7) << 4) + (s & 15);
        int ko = (s >> 4) & 7;
        aOff[j] = (size_t)(row0 + rl) * DIMv + ko * 8;
        int grow = (rl < 64) ? (h * Dv + rl) : (DIMv + h * Dv + (rl - 64));
        bOff[j] = (size_t)grow * DIMv + ko * 8;
        ldsA[j] = c * 1024;             // bytes (A half, 16KB)
        ldsB[j] = 16384 + c * 1024;     // bytes (B half, 16KB)
    }

    const int wm = wu >> 1, wn = wu & 1;
    f32x4 acc[4][4];
#pragma unroll
    for (int i = 0; i < 4; ++i)
#pragma unroll
        for (int j = 0; j < 4; ++j) acc[i][j] = (f32x4){0.f, 0.f, 0.f, 0.f};

    // ---- m97-style K-loop: stage -> sync (drains vmcnt) -> compute -> sync
    for (int k0 = 0; k0 < DIMv; k0 += BK) {
#pragma unroll
        for (int j = 0; j < 4; ++j) {
            GLOAD(xh + aOff[j] + k0, sBytes + ldsA[j]);
            GLOAD(qkh + bOff[j] + k0, sBytes + ldsB[j]);
        }
        __syncthreads();

        _Float16* sH = (_Float16*)sBytes;
#pragma unroll
        for (int kk = 0; kk < 2; ++kk) {
            const int fo = (kk * 4 + rg) * 16 + dm;
            half8 af[4], bf[4];
#pragma unroll
            for (int i = 0; i < 4; ++i)
                af[i] = *(half8*)(sH + ((wm * 4 + i) * 128 + fo) * 8);
#pragma unroll
            for (int j = 0; j < 4; ++j)
                bf[j] = *(half8*)(sH + (1024 + (wn * 4 + j) * 128 + fo) * 8);
#pragma unroll
            for (int i = 0; i < 4; ++i)
#pragma unroll
                for (int j = 0; j < 4; ++j)
                    acc[i][j] = __builtin_amdgcn_mfma_f32_16x16x32_f16(af[i], bf[j], acc[i][j], 0, 0, 0);
        }
        __syncthreads();
    }

    // ---- in-register quadrant reduce (no C-tile):
    // wave (wm,wn): rows wm*64..+64, cols = q-features (wn=0) or k-features (wn=1)
    {
        const float* sW = wn ? &sWr[0][0] : &sWe[0][0];
        float wv[4][Rv];
#pragma unroll
        for (int j = 0; j < 4; ++j)
#pragma unroll
            for (int r = 0; r < Rv; ++r)
                wv[j][r] = sW[(j * 16 + dm) * Rv + r];

#pragma unroll
        for (int i = 0; i < 4; ++i)
#pragma unroll
            for (int reg = 0; reg < 4; ++reg) {
                float red[6] = {0.f, 0.f, 0.f, 0.f, 0.f, 0.f};
#pragma unroll
                for (int j = 0; j < 4; ++j) {
                    float v = acc[i][j][reg];
                    red[0] = fmaf(v, v, red[0]);
#pragma unroll
                    for (int r = 0; r < Rv; ++r)
                        red[1 + r] = fmaf(v, wv[j][r], red[1 + r]);
                }
#pragma unroll
                for (int off = 8; off > 0; off >>= 1)
#pragma unroll
                    for (int u = 0; u < 6; ++u)
                        red[u] += __shfl_xor(red[u], off, 64);
                if (dm == 0) {
                    const int rowI = wm * 64 + i * 16 + rg * 4 + reg;
#pragma unroll
                    for (int u = 0; u < 6; ++u)
                        sRed[rowI][wn * 6 + u] = red[u];
                }
            }
    }
    __syncthreads();

    // ---- epilogue: 4 rows/wave/pass; lane = rg*16 + dm, d-slice = dm*4..+4
    const int d0 = dm * 4;
    float fwv[4][Rv], fbv[4];
#pragma unroll
    for (int i = 0; i < 4; ++i) {
        fbv[i] = sFb[d0 + i];
#pragma unroll
        for (int r = 0; r < Rv; ++r) fwv[i][r] = sFw[d0 + i][r];
    }

    for (int p = 0; p < 8; ++p) {
        const int row = w * 32 + p * 4 + rg;
        const int nf = row0 + row;             // flat b*N+n
        const int n = nf & (Nv - 1);
        const float mk = mask[nf];
        const float amk = fabsf(mk);

        // mask applied post-reduction: ||mk*q|| = |mk|*||q||, (mk*q)·we = mk*(q·we)
        const float qn = fmaxf(amk * sqrtf(sRed[row][0]), 1e-12f);
        const float kn = fmaxf(amk * sqrtf(sRed[row][6]), 1e-12f);
        const float iq = mk / qn;
        const float ik = mk / kn;

        float esc[Rv], rsc[Rv], v1[Rv];
#pragma unroll
        for (int r = 0; r < Rv; ++r) {
            esc[r] = sRed[row][1 + r] * iq;
            rsc[r] = sRed[row][7 + r] * ik;
            v1[r] = (esc[r] + rsc[r]) * sLam2[r];
        }

        const size_t eb = (((size_t)(nf >> 11) * Hv + h) * Nv + n) * Rv;
        float ev[Rv];
#pragma unroll
        for (int u = 0; u < Rv; ++u) ev[u] = eps[eb + u];

        float smp[Rv];
#pragma unroll
        for (int c = 0; c < Rv; ++c) {
            float mn = 0.f;
#pragma unroll
            for (int a = 0; a < Rv; ++a) mn = fmaf(v1[a], sMu[a][c], mn);
            float nz = 0.f;
#pragma unroll
            for (int u = 0; u < Rv; ++u) {
                float s = 0.f;
#pragma unroll
                for (int a = 0; a < Rv; ++a) s = fmaf(v1[a], sS[a][u][c], s);
                nz = fmaf(s, ev[u], nz);
            }
            smp[c] = mn + nz;
        }

        float4 ao;
        float aov[4];
#pragma unroll
        for (int i = 0; i < 4; ++i) {
            float a = fbv[i];
#pragma unroll
            for (int r = 0; r < Rv; ++r) a = fmaf(smp[r], fwv[i][r], a);
            aov[i] = a;
        }
        ao.x = aov[0]; ao.y = aov[1]; ao.z = aov[2]; ao.w = aov[3];
        *(float4*)&out[ATTN_OFF + (size_t)nf * DIMv + h * Dv + d0] = ao;

        if (dm == 0) {
#pragma unroll
            for (int r = 0; r < Rv; ++r) {
                out[ESC_OFF + eb + r] = esc[r];
                out[RSC_OFF + eb + r] = rsc[r];
            }
        }
    }
}

extern "C" void kernel_launch(void* const* d_in, const int* in_sizes, int n_in,
                              void* d_out, int out_size, void* d_ws, size_t ws_size,
                              hipStream_t stream) {
    const float* x        = (const float*)d_in[0];
    const float* mask     = (const float*)d_in[1];
    const float* eps      = (const float*)d_in[2];
    const float* qk_w     = (const float*)d_in[3];
    const float* we_p     = (const float*)d_in[4];
    const float* wr_p     = (const float*)d_in[5];
    const float* log_lam  = (const float*)d_in[6];
    const float* m_u      = (const float*)d_in[7];
    const float* s_tri    = (const float*)d_in[8];
    const float* log_ssqrt= (const float*)d_in[9];
    const float* fw_w     = (const float*)d_in[10];
    const float* fw_b     = (const float*)d_in[11];
    float* out = (float*)d_out;

    _Float16* xh  = (_Float16*)d_ws;
    _Float16* qkh = xh + XHALFS;

    convert_fp16<<<dim3(CONV_BLOCKS + 1), 256, 0, stream>>>(x, qk_w, xh, qkh,
                                                            log_lam, m_u, s_tri, log_ssqrt, out);
    svgp_main<<<dim3(2048), 256, 0, stream>>>(xh, qkh, x, mask, eps, we_p, wr_p,
                                              log_lam, m_u, s_tri, log_ssqrt, fw_w, fw_b, out);
}

// Round 8
// 359.177 us; speedup vs baseline: 2.9145x; 2.9145x over previous
//
#include <hip/hip_runtime.h>
#include <math.h>

#define Bv 8
#define Nv 2048
#define DIMv 1024
#define Hv 16
#define Dv 64
#define Rv 5
#define RMv 10

// output layout (flat concat, fp32)
#define ATTN_OFF 0
#define ESC_OFF (Bv * Nv * DIMv)              // 16777216
#define RSC_OFF (ESC_OFF + Bv * Hv * Nv * Rv) // 18087936
#define KL_OFF  (RSC_OFF + Bv * Hv * Nv * Rv) // 19398656

#define BMt 128      // rows per block
#define BK 64        // fp16 k-chunk per phase (full 128B cache lines per row)

#define XHALFS (Bv * Nv * DIMv)     // 16777216
#define QKHALFS (2 * DIMv * DIMv)   // 2097152
#define CONV_BLOCKS ((XHALFS + QKHALFS) / 8 / 256)   // 9216

using half8 = __attribute__((ext_vector_type(8))) _Float16;
using f32x4 = __attribute__((ext_vector_type(4))) float;

#define GLOAD(gp, lp)                                                      \
    __builtin_amdgcn_global_load_lds(                                      \
        (const __attribute__((address_space(1))) void*)(gp),               \
        (__attribute__((address_space(3))) void*)(lp), 16, 0, 0)

// ---- pre-pass: fp32 -> fp16 of x and qk_w into workspace; last block does KL
__global__ __launch_bounds__(256)
void convert_fp16(const float* __restrict__ x, const float* __restrict__ qk,
                  _Float16* __restrict__ xh, _Float16* __restrict__ qkh,
                  const float* __restrict__ log_lam, const float* __restrict__ m_u,
                  const float* __restrict__ s_tri, const float* __restrict__ log_ssqrt,
                  float* __restrict__ out)
{
    __shared__ float red[256];
    const int t = threadIdx.x;

    if (blockIdx.x == CONV_BLOCKS) {
        // ---- KL reduction (single block)
        float acc = 0.f;
        for (int idx = t; idx < Hv * Rv * Rv * Rv; idx += 256) {
            int hh = idx / 125;
            int rem = idx % 125;
            int a = rem / 25, u = (rem / 5) % 5, c = rem % 5;
            float S = 0.f;
            if (u == c)      S = expf(log_ssqrt[(hh * Rv + a) * Rv + u]);
            else if (u > c)  S = s_tri[((hh * Rv + a) * Rv + u) * Rv + c];
            float lam2 = expf(2.f * log_lam[hh * Rv + a]);
            float z = lam2 * S;
            acc += 0.5f * z * z;
        }
        for (int idx = t; idx < Hv * Rv * Rv; idx += 256) {
            int hh = idx / 25, a = (idx / 5) % 5;
            float e4 = expf(4.f * log_lam[hh * Rv + a]);
            float mu = m_u[idx];
            acc += 0.5f * e4 * mu * mu;
            acc -= log_ssqrt[idx];
        }
        for (int idx = t; idx < Hv * Rv; idx += 256) acc -= 2.f * (float)Rv * log_lam[idx];

        red[t] = acc;
        __syncthreads();
        for (int s = 128; s > 0; s >>= 1) {
            if (t < s) red[t] += red[t + s];
            __syncthreads();
        }
        if (t == 0) out[KL_OFF] = red[0] - 0.5f * (float)(Rv * Rv * Hv);
        return;
    }

    size_t i = ((size_t)blockIdx.x * 256 + t) * 8;
    const float* src;
    _Float16* dst;
    if (i < XHALFS) { src = x + i; dst = xh + i; }
    else            { src = qk + (i - XHALFS); dst = qkh + (i - XHALFS); }
    float4 v0 = *(const float4*)src;
    float4 v1 = *(const float4*)(src + 4);
    half8 hv = {(_Float16)v0.x, (_Float16)v0.y, (_Float16)v0.z, (_Float16)v0.w,
                (_Float16)v1.x, (_Float16)v1.y, (_Float16)v1.z, (_Float16)v1.w};
    *(half8*)dst = hv;
}

// grid: 2048 1-D (xcd-affine: id&7 -> heads {2x,2x+1}); block: 256 = 4 waves
// single-buffer m97-style schedule; 37.9KB LDS -> 4 blocks/CU by LDS.
// NOTE: __launch_bounds__ min-waves arg MUST stay 2: on this compiler the
// VGPR cap is ~256/w, so w=4 forced 64 VGPRs -> acc[4][4] spilled to scratch
// (r2/r7: FETCH=WRITE~2GB symmetric, 14x traffic). w=2 caps at 128 >= the
// ~124 this kernel needs; occupancy is then LDS-limited at 4 blocks/CU.
__global__ __launch_bounds__(256, 2)
void svgp_main(const _Float16* __restrict__ xh, const _Float16* __restrict__ qkh,
               const float* __restrict__ x, const float* __restrict__ mask,
               const float* __restrict__ eps,
               const float* __restrict__ we_p, const float* __restrict__ wr_p,
               const float* __restrict__ log_lam, const float* __restrict__ m_u,
               const float* __restrict__ s_tri, const float* __restrict__ log_ssqrt,
               const float* __restrict__ fw_w, const float* __restrict__ fw_b,
               float* __restrict__ out)
{
    const int id = blockIdx.x;
    const int h = 2 * (id & 7) + ((id >> 3) & 1);
    const int rowTile = id >> 4;           // 0..127
    const int row0 = rowTile * BMt;        // flat row base (b*N + n)
    const int b0 = row0 >> 11;             // batch (tile never straddles b)
    const int t = threadIdx.x;
    const int lane = t & 63;
    const int w = t >> 6;
    const int wu = __builtin_amdgcn_readfirstlane(w);   // wave-uniform
    const int dm = lane & 15;
    const int rg = lane >> 4;

    // LDS: single staging buffer A 16KB + B 16KB; aliased (post K-loop) with sRed
    __shared__ float4 sStageV[2048];       // 32 KB
    char* sBytes = (char*)sStageV;
    float (*sRed)[12] = (float (*)[12])sStageV;

    __shared__ float sS[Rv][Rv][Rv];
    __shared__ float sMu[Rv][Rv];
    __shared__ float sFw[Dv][Rv];
    __shared__ float sFb[Dv];
    __shared__ float sLam2[Rv];
    __shared__ float sWe[Dv][Rv];
    __shared__ float sWr[Dv][Rv];

    // ---- small tables (reads happen only after K-loop barriers)
    if (t < 125) {
        int a = t / 25, u = (t % 25) / 5, c = t % 5;
        float v = 0.f;
        if (u == c)      v = expf(log_ssqrt[(h * Rv + a) * Rv + u]);
        else if (u > c)  v = s_tri[((h * Rv + a) * Rv + u) * Rv + c];
        sS[a][u][c] = v;
    }
    if (t >= 128 && t < 153) { int i = t - 128; sMu[i / 5][i % 5] = m_u[h * Rv * Rv + i]; }
    if (t >= 160 && t < 165) sLam2[t - 160] = expf(2.f * log_lam[h * Rv + (t - 160)]);
    if (t >= 192 && t < 256) sFb[t - 192] = fw_b[t - 192];
    if (t < 320) sFw[t / Rv][t % Rv] = fw_w[t];
    { int t2 = t + 256; if (t2 < 320) sFw[t2 / Rv][t2 % Rv] = fw_w[t2]; }

    // ---- we/wr once per block (wave 0, lane = d), fp32
    if (t < 64) {
        float xv[RMv];
#pragma unroll
        for (int m = 0; m < RMv; ++m) {
            int nidx = (m == RMv - 1) ? (Nv - 1) : (int)((float)m * (2047.0f / 9.0f));
            xv[m] = x[((size_t)b0 * Nv + nidx) * DIMv + h * Dv + t];
        }
#pragma unroll
        for (int rr = 0; rr < Rv; ++rr) {
            float sw = 0.f, sr = 0.f;
#pragma unroll
            for (int m = 0; m < RMv; ++m) {
                sw = fmaf(xv[m], we_p[(h * RMv + m) * Rv + rr], sw);
                sr = fmaf(xv[m], wr_p[(h * RMv + m) * Rv + rr], sr);
            }
            sWe[t][rr] = sw; sWr[t][rr] = sr;
        }
    }

    // ---- staging address precompute (k0-invariant), BK=64 full-line phases
    // slot s = c*64 + lane; rl = (s>>7)*16 + (s&15); ko = (s>>4)&7
    // LDS fragment-major: slot = mtile*128 + ko*16 + mrow, 8 halfs (16B) per slot
    size_t aOff[4], bOff[4];
    int ldsA[4], ldsB[4];
#pragma unroll
    for (int j = 0; j < 4; ++j) {
        int c = wu * 4 + j;
        int s = c * 64 + lane;
        int rl = ((s >> 7) << 4) + (s & 15);
        int ko = (s >> 4) & 7;
        aOff[j] = (size_t)(row0 + rl) * DIMv + ko * 8;
        int grow = (rl < 64) ? (h * Dv + rl) : (DIMv + h * Dv + (rl - 64));
        bOff[j] = (size_t)grow * DIMv + ko * 8;
        ldsA[j] = c * 1024;             // bytes (A half, 16KB)
        ldsB[j] = 16384 + c * 1024;     // bytes (B half, 16KB)
    }

    const int wm = wu >> 1, wn = wu & 1;
    f32x4 acc[4][4];
#pragma unroll
    for (int i = 0; i < 4; ++i)
#pragma unroll
        for (int j = 0; j < 4; ++j) acc[i][j] = (f32x4){0.f, 0.f, 0.f, 0.f};

    // ---- m97-style K-loop: stage -> sync (drains vmcnt) -> compute -> sync
    for (int k0 = 0; k0 < DIMv; k0 += BK) {
#pragma unroll
        for (int j = 0; j < 4; ++j) {
            GLOAD(xh + aOff[j] + k0, sBytes + ldsA[j]);
            GLOAD(qkh + bOff[j] + k0, sBytes + ldsB[j]);
        }
        __syncthreads();

        _Float16* sH = (_Float16*)sBytes;
#pragma unroll
        for (int kk = 0; kk < 2; ++kk) {
            const int fo = (kk * 4 + rg) * 16 + dm;
            half8 af[4], bf[4];
#pragma unroll
            for (int i = 0; i < 4; ++i)
                af[i] = *(half8*)(sH + ((wm * 4 + i) * 128 + fo) * 8);
#pragma unroll
            for (int j = 0; j < 4; ++j)
                bf[j] = *(half8*)(sH + (1024 + (wn * 4 + j) * 128 + fo) * 8);
#pragma unroll
            for (int i = 0; i < 4; ++i)
#pragma unroll
                for (int j = 0; j < 4; ++j)
                    acc[i][j] = __builtin_amdgcn_mfma_f32_16x16x32_f16(af[i], bf[j], acc[i][j], 0, 0, 0);
        }
        __syncthreads();
    }

    // ---- in-register quadrant reduce (no C-tile):
    // wave (wm,wn): rows wm*64..+64, cols = q-features (wn=0) or k-features (wn=1)
    {
        const float* sW = wn ? &sWr[0][0] : &sWe[0][0];
        float wv[4][Rv];
#pragma unroll
        for (int j = 0; j < 4; ++j)
#pragma unroll
            for (int r = 0; r < Rv; ++r)
                wv[j][r] = sW[(j * 16 + dm) * Rv + r];

#pragma unroll
        for (int i = 0; i < 4; ++i)
#pragma unroll
            for (int reg = 0; reg < 4; ++reg) {
                float red[6] = {0.f, 0.f, 0.f, 0.f, 0.f, 0.f};
#pragma unroll
                for (int j = 0; j < 4; ++j) {
                    float v = acc[i][j][reg];
                    red[0] = fmaf(v, v, red[0]);
#pragma unroll
                    for (int r = 0; r < Rv; ++r)
                        red[1 + r] = fmaf(v, wv[j][r], red[1 + r]);
                }
#pragma unroll
                for (int off = 8; off > 0; off >>= 1)
#pragma unroll
                    for (int u = 0; u < 6; ++u)
                        red[u] += __shfl_xor(red[u], off, 64);
                if (dm == 0) {
                    const int rowI = wm * 64 + i * 16 + rg * 4 + reg;
#pragma unroll
                    for (int u = 0; u < 6; ++u)
                        sRed[rowI][wn * 6 + u] = red[u];
                }
            }
    }
    __syncthreads();

    // ---- epilogue: 4 rows/wave/pass; lane = rg*16 + dm, d-slice = dm*4..+4
    const int d0 = dm * 4;
    float fwv[4][Rv], fbv[4];
#pragma unroll
    for (int i = 0; i < 4; ++i) {
        fbv[i] = sFb[d0 + i];
#pragma unroll
        for (int r = 0; r < Rv; ++r) fwv[i][r] = sFw[d0 + i][r];
    }

    for (int p = 0; p < 8; ++p) {
        const int row = w * 32 + p * 4 + rg;
        const int nf = row0 + row;             // flat b*N+n
        const int n = nf & (Nv - 1);
        const float mk = mask[nf];
        const float amk = fabsf(mk);

        // mask applied post-reduction: ||mk*q|| = |mk|*||q||, (mk*q)·we = mk*(q·we)
        const float qn = fmaxf(amk * sqrtf(sRed[row][0]), 1e-12f);
        const float kn = fmaxf(amk * sqrtf(sRed[row][6]), 1e-12f);
        const float iq = mk / qn;
        const float ik = mk / kn;

        float esc[Rv], rsc[Rv], v1[Rv];
#pragma unroll
        for (int r = 0; r < Rv; ++r) {
            esc[r] = sRed[row][1 + r] * iq;
            rsc[r] = sRed[row][7 + r] * ik;
            v1[r] = (esc[r] + rsc[r]) * sLam2[r];
        }

        const size_t eb = (((size_t)(nf >> 11) * Hv + h) * Nv + n) * Rv;
        float ev[Rv];
#pragma unroll
        for (int u = 0; u < Rv; ++u) ev[u] = eps[eb + u];

        float smp[Rv];
#pragma unroll
        for (int c = 0; c < Rv; ++c) {
            float mn = 0.f;
#pragma unroll
            for (int a = 0; a < Rv; ++a) mn = fmaf(v1[a], sMu[a][c], mn);
            float nz = 0.f;
#pragma unroll
            for (int u = 0; u < Rv; ++u) {
                float s = 0.f;
#pragma unroll
                for (int a = 0; a < Rv; ++a) s = fmaf(v1[a], sS[a][u][c], s);
                nz = fmaf(s, ev[u], nz);
            }
            smp[c] = mn + nz;
        }

        float4 ao;
        float aov[4];
#pragma unroll
        for (int i = 0; i < 4; ++i) {
            float a = fbv[i];
#pragma unroll
            for (int r = 0; r < Rv; ++r) a = fmaf(smp[r], fwv[i][r], a);
            aov[i] = a;
        }
        ao.x = aov[0]; ao.y = aov[1]; ao.z = aov[2]; ao.w = aov[3];
        *(float4*)&out[ATTN_OFF + (size_t)nf * DIMv + h * Dv + d0] = ao;

        if (dm == 0) {
#pragma unroll
            for (int r = 0; r < Rv; ++r) {
                out[ESC_OFF + eb + r] = esc[r];
                out[RSC_OFF + eb + r] = rsc[r];
            }
        }
    }
}

extern "C" void kernel_launch(void* const* d_in, const int* in_sizes, int n_in,
                              void* d_out, int out_size, void* d_ws, size_t ws_size,
                              hipStream_t stream) {
    const float* x        = (const float*)d_in[0];
    const float* mask     = (const float*)d_in[1];
    const float* eps      = (const float*)d_in[2];
    const float* qk_w     = (const float*)d_in[3];
    const float* we_p     = (const float*)d_in[4];
    const float* wr_p     = (const float*)d_in[5];
    const float* log_lam  = (const float*)d_in[6];
    const float* m_u      = (const float*)d_in[7];
    const float* s_tri    = (const float*)d_in[8];
    const float* log_ssqrt= (const float*)d_in[9];
    const float* fw_w     = (const float*)d_in[10];
    const float* fw_b     = (const float*)d_in[11];
    float* out = (float*)d_out;

    _Float16* xh  = (_Float16*)d_ws;
    _Float16* qkh = xh + XHALFS;

    convert_fp16<<<dim3(CONV_BLOCKS + 1), 256, 0, stream>>>(x, qk_w, xh, qkh,
                                                            log_lam, m_u, s_tri, log_ssqrt, out);
    svgp_main<<<dim3(2048), 256, 0, stream>>>(xh, qkh, x, mask, eps, we_p, wr_p,
                                              log_lam, m_u, s_tri, log_ssqrt, fw_w, fw_b, out);
}

// Round 9
// 351.486 us; speedup vs baseline: 2.9783x; 1.0219x over previous
//
#include <hip/hip_runtime.h>
#include <math.h>

#define Bv 8
#define Nv 2048
#define DIMv 1024
#define Hv 16
#define Dv 64
#define Rv 5
#define RMv 10

// output layout (flat concat, fp32)
#define ATTN_OFF 0
#define ESC_OFF (Bv * Nv * DIMv)              // 16777216
#define RSC_OFF (ESC_OFF + Bv * Hv * Nv * Rv) // 18087936
#define KL_OFF  (RSC_OFF + Bv * Hv * Nv * Rv) // 19398656

#define BMt 128      // rows per block
#define BK 128       // fp16 k-chunk per phase (two 128B lines per row)

#define XHALFS (Bv * Nv * DIMv)     // 16777216
#define QKHALFS (2 * DIMv * DIMv)   // 2097152
#define CONV_BLOCKS ((XHALFS + QKHALFS) / 8 / 256)   // 9216

using half8 = __attribute__((ext_vector_type(8))) _Float16;
using f32x4 = __attribute__((ext_vector_type(4))) float;

#define GLOAD(gp, lp)                                                      \
    __builtin_amdgcn_global_load_lds(                                      \
        (const __attribute__((address_space(1))) void*)(gp),               \
        (__attribute__((address_space(3))) void*)(lp), 16, 0, 0)

// ---- pre-pass: fp32 -> fp16 of x and qk_w into workspace; last block does KL
__global__ __launch_bounds__(256)
void convert_fp16(const float* __restrict__ x, const float* __restrict__ qk,
                  _Float16* __restrict__ xh, _Float16* __restrict__ qkh,
                  const float* __restrict__ log_lam, const float* __restrict__ m_u,
                  const float* __restrict__ s_tri, const float* __restrict__ log_ssqrt,
                  float* __restrict__ out)
{
    __shared__ float red[256];
    const int t = threadIdx.x;

    if (blockIdx.x == CONV_BLOCKS) {
        // ---- KL reduction (single block)
        float acc = 0.f;
        for (int idx = t; idx < Hv * Rv * Rv * Rv; idx += 256) {
            int hh = idx / 125;
            int rem = idx % 125;
            int a = rem / 25, u = (rem / 5) % 5, c = rem % 5;
            float S = 0.f;
            if (u == c)      S = expf(log_ssqrt[(hh * Rv + a) * Rv + u]);
            else if (u > c)  S = s_tri[((hh * Rv + a) * Rv + u) * Rv + c];
            float lam2 = expf(2.f * log_lam[hh * Rv + a]);
            float z = lam2 * S;
            acc += 0.5f * z * z;
        }
        for (int idx = t; idx < Hv * Rv * Rv; idx += 256) {
            int hh = idx / 25, a = (idx / 5) % 5;
            float e4 = expf(4.f * log_lam[hh * Rv + a]);
            float mu = m_u[idx];
            acc += 0.5f * e4 * mu * mu;
            acc -= log_ssqrt[idx];
        }
        for (int idx = t; idx < Hv * Rv; idx += 256) acc -= 2.f * (float)Rv * log_lam[idx];

        red[t] = acc;
        __syncthreads();
        for (int s = 128; s > 0; s >>= 1) {
            if (t < s) red[t] += red[t + s];
            __syncthreads();
        }
        if (t == 0) out[KL_OFF] = red[0] - 0.5f * (float)(Rv * Rv * Hv);
        return;
    }

    size_t i = ((size_t)blockIdx.x * 256 + t) * 8;
    const float* src;
    _Float16* dst;
    if (i < XHALFS) { src = x + i; dst = xh + i; }
    else            { src = qk + (i - XHALFS); dst = qkh + (i - XHALFS); }
    float4 v0 = *(const float4*)src;
    float4 v1 = *(const float4*)(src + 4);
    half8 hv = {(_Float16)v0.x, (_Float16)v0.y, (_Float16)v0.z, (_Float16)v0.w,
                (_Float16)v1.x, (_Float16)v1.y, (_Float16)v1.z, (_Float16)v1.w};
    *(half8*)dst = hv;
}

// grid: 2048 1-D (xcd-affine: id&7 -> heads {2x,2x+1}); block: 256 = 4 waves
// single 64KB buffer, 8 fat phases (BK=128). 69.7KB LDS -> 2 blocks/CU.
// NOTE: __launch_bounds__ min-waves arg MUST stay 2: unified VGPR+AGPR file,
// w=4 caps total at 128 -> acc (64 AGPR) + 64 arch -> everything spills
// (r2/r7: FETCH=WRITE~2GB symmetric). w=2 caps at 256: ~140 arch + 64 acc OK.
// Occupancy is register-pinned at 2 waves/SIMD (8 waves/CU) regardless.
__global__ __launch_bounds__(256, 2)
void svgp_main(const _Float16* __restrict__ xh, const _Float16* __restrict__ qkh,
               const float* __restrict__ x, const float* __restrict__ mask,
               const float* __restrict__ eps,
               const float* __restrict__ we_p, const float* __restrict__ wr_p,
               const float* __restrict__ log_lam, const float* __restrict__ m_u,
               const float* __restrict__ s_tri, const float* __restrict__ log_ssqrt,
               const float* __restrict__ fw_w, const float* __restrict__ fw_b,
               float* __restrict__ out)
{
    const int id = blockIdx.x;
    const int h = 2 * (id & 7) + ((id >> 3) & 1);
    const int rowTile = id >> 4;           // 0..127
    const int row0 = rowTile * BMt;        // flat row base (b*N + n)
    const int b0 = row0 >> 11;             // batch (tile never straddles b)
    const int t = threadIdx.x;
    const int lane = t & 63;
    const int w = t >> 6;
    const int wu = __builtin_amdgcn_readfirstlane(w);   // wave-uniform
    const int dm = lane & 15;
    const int rg = lane >> 4;

    // LDS: single staging buffer A 32KB + B 32KB; aliased (post K-loop) with sRed
    __shared__ float4 sStageV[4096];       // 64 KB
    char* sBytes = (char*)sStageV;
    float (*sRed)[12] = (float (*)[12])sStageV;

    __shared__ float sS[Rv][Rv][Rv];
    __shared__ float sMu[Rv][Rv];
    __shared__ float sFw[Dv][Rv];
    __shared__ float sFb[Dv];
    __shared__ float sLam2[Rv];
    __shared__ float sWe[Dv][Rv];
    __shared__ float sWr[Dv][Rv];

    // ---- small tables (reads happen only after K-loop barriers)
    if (t < 125) {
        int a = t / 25, u = (t % 25) / 5, c = t % 5;
        float v = 0.f;
        if (u == c)      v = expf(log_ssqrt[(h * Rv + a) * Rv + u]);
        else if (u > c)  v = s_tri[((h * Rv + a) * Rv + u) * Rv + c];
        sS[a][u][c] = v;
    }
    if (t >= 128 && t < 153) { int i = t - 128; sMu[i / 5][i % 5] = m_u[h * Rv * Rv + i]; }
    if (t >= 160 && t < 165) sLam2[t - 160] = expf(2.f * log_lam[h * Rv + (t - 160)]);
    if (t >= 192 && t < 256) sFb[t - 192] = fw_b[t - 192];
    if (t < 320) sFw[t / Rv][t % Rv] = fw_w[t];
    { int t2 = t + 256; if (t2 < 320) sFw[t2 / Rv][t2 % Rv] = fw_w[t2]; }

    // ---- we/wr once per block (wave 0, lane = d), fp32
    if (t < 64) {
        float xv[RMv];
#pragma unroll
        for (int m = 0; m < RMv; ++m) {
            int nidx = (m == RMv - 1) ? (Nv - 1) : (int)((float)m * (2047.0f / 9.0f));
            xv[m] = x[((size_t)b0 * Nv + nidx) * DIMv + h * Dv + t];
        }
#pragma unroll
        for (int rr = 0; rr < Rv; ++rr) {
            float sw = 0.f, sr = 0.f;
#pragma unroll
            for (int m = 0; m < RMv; ++m) {
                sw = fmaf(xv[m], we_p[(h * RMv + m) * Rv + rr], sw);
                sr = fmaf(xv[m], wr_p[(h * RMv + m) * Rv + rr], sr);
            }
            sWe[t][rr] = sw; sWr[t][rr] = sr;
        }
    }

    // ---- staging address precompute (k0-invariant), BK=128 phases
    // 2048 slots per matrix (16B each). slot s = c*64 + lane, c = wu*8 + j.
    // mtile = s>>8 (16 rows), ko = (s>>4)&15, mrow = s&15;
    // rl = mtile*16 + mrow; LDS layout slot = mtile*256 + ko*16 + mrow.
    // j&3 steps ko by 4 (+32 halfs global); j>>2 steps mtile by 1 (+16 rows).
    const int s0 = wu * 512 + lane;
    const int rl0 = ((s0 >> 8) << 4) + (s0 & 15);
    const int ko0 = (s0 >> 4) & 15;
    const size_t aOff0 = (size_t)(row0 + rl0) * DIMv + ko0 * 8;
    const int grow0 = (rl0 < 64) ? (h * Dv + rl0) : (DIMv + h * Dv + (rl0 - 64));
    const size_t bOff0 = (size_t)grow0 * DIMv + ko0 * 8;
    const int ldsA0 = wu * 8192;            // bytes (A half, 32KB total)
    const int ldsB0 = 32768 + wu * 8192;    // bytes (B half, 32KB total)

    const int wm = wu >> 1, wn = wu & 1;
    f32x4 acc[4][4];
#pragma unroll
    for (int i = 0; i < 4; ++i)
#pragma unroll
        for (int j = 0; j < 4; ++j) acc[i][j] = (f32x4){0.f, 0.f, 0.f, 0.f};

    // ---- m97-style K-loop, 8 fat phases: stage 64KB -> sync -> 128 MFMA -> sync
    for (int k0 = 0; k0 < DIMv; k0 += BK) {
#pragma unroll
        for (int j = 0; j < 8; ++j) {
            const int gofs = (j >> 2) * 16 * DIMv + (j & 3) * 32;  // halfs
            GLOAD(xh + aOff0 + gofs + k0, sBytes + ldsA0 + j * 1024);
            GLOAD(qkh + bOff0 + gofs + k0, sBytes + ldsB0 + j * 1024);
        }
        __syncthreads();

        _Float16* sH = (_Float16*)sBytes;
#pragma unroll
        for (int kk = 0; kk < 4; ++kk) {
            const int fo = (kk * 4 + rg) * 16 + dm;
            half8 af[4], bf[4];
#pragma unroll
            for (int i = 0; i < 4; ++i)
                af[i] = *(half8*)(sH + ((wm * 4 + i) * 256 + fo) * 8);
#pragma unroll
            for (int j = 0; j < 4; ++j)
                bf[j] = *(half8*)(sH + ((2048 + (wn * 4 + j) * 256 + fo)) * 8);
#pragma unroll
            for (int i = 0; i < 4; ++i)
#pragma unroll
                for (int j = 0; j < 4; ++j)
                    acc[i][j] = __builtin_amdgcn_mfma_f32_16x16x32_f16(af[i], bf[j], acc[i][j], 0, 0, 0);
        }
        __syncthreads();
    }

    // ---- in-register quadrant reduce (no C-tile):
    // wave (wm,wn): rows wm*64..+64, cols = q-features (wn=0) or k-features (wn=1)
    {
        const float* sW = wn ? &sWr[0][0] : &sWe[0][0];
        float wv[4][Rv];
#pragma unroll
        for (int j = 0; j < 4; ++j)
#pragma unroll
            for (int r = 0; r < Rv; ++r)
                wv[j][r] = sW[(j * 16 + dm) * Rv + r];

#pragma unroll
        for (int i = 0; i < 4; ++i)
#pragma unroll
            for (int reg = 0; reg < 4; ++reg) {
                float red[6] = {0.f, 0.f, 0.f, 0.f, 0.f, 0.f};
#pragma unroll
                for (int j = 0; j < 4; ++j) {
                    float v = acc[i][j][reg];
                    red[0] = fmaf(v, v, red[0]);
#pragma unroll
                    for (int r = 0; r < Rv; ++r)
                        red[1 + r] = fmaf(v, wv[j][r], red[1 + r]);
                }
#pragma unroll
                for (int off = 8; off > 0; off >>= 1)
#pragma unroll
                    for (int u = 0; u < 6; ++u)
                        red[u] += __shfl_xor(red[u], off, 64);
                if (dm == 0) {
                    const int rowI = wm * 64 + i * 16 + rg * 4 + reg;
#pragma unroll
                    for (int u = 0; u < 6; ++u)
                        sRed[rowI][wn * 6 + u] = red[u];
                }
            }
    }
    __syncthreads();

    // ---- epilogue: 4 rows/wave/pass; lane = rg*16 + dm, d-slice = dm*4..+4
    const int d0 = dm * 4;
    float fwv[4][Rv], fbv[4];
#pragma unroll
    for (int i = 0; i < 4; ++i) {
        fbv[i] = sFb[d0 + i];
#pragma unroll
        for (int r = 0; r < Rv; ++r) fwv[i][r] = sFw[d0 + i][r];
    }

    for (int p = 0; p < 8; ++p) {
        const int row = w * 32 + p * 4 + rg;
        const int nf = row0 + row;             // flat b*N+n
        const int n = nf & (Nv - 1);
        const float mk = mask[nf];
        const float amk = fabsf(mk);

        // mask applied post-reduction: ||mk*q|| = |mk|*||q||, (mk*q)·we = mk*(q·we)
        const float qn = fmaxf(amk * sqrtf(sRed[row][0]), 1e-12f);
        const float kn = fmaxf(amk * sqrtf(sRed[row][6]), 1e-12f);
        const float iq = mk / qn;
        const float ik = mk / kn;

        float esc[Rv], rsc[Rv], v1[Rv];
#pragma unroll
        for (int r = 0; r < Rv; ++r) {
            esc[r] = sRed[row][1 + r] * iq;
            rsc[r] = sRed[row][7 + r] * ik;
            v1[r] = (esc[r] + rsc[r]) * sLam2[r];
        }

        const size_t eb = (((size_t)(nf >> 11) * Hv + h) * Nv + n) * Rv;
        float ev[Rv];
#pragma unroll
        for (int u = 0; u < Rv; ++u) ev[u] = eps[eb + u];

        float smp[Rv];
#pragma unroll
        for (int c = 0; c < Rv; ++c) {
            float mn = 0.f;
#pragma unroll
            for (int a = 0; a < Rv; ++a) mn = fmaf(v1[a], sMu[a][c], mn);
            float nz = 0.f;
#pragma unroll
            for (int u = 0; u < Rv; ++u) {
                float s = 0.f;
#pragma unroll
                for (int a = 0; a < Rv; ++a) s = fmaf(v1[a], sS[a][u][c], s);
                nz = fmaf(s, ev[u], nz);
            }
            smp[c] = mn + nz;
        }

        float4 ao;
        float aov[4];
#pragma unroll
        for (int i = 0; i < 4; ++i) {
            float a = fbv[i];
#pragma unroll
            for (int r = 0; r < Rv; ++r) a = fmaf(smp[r], fwv[i][r], a);
            aov[i] = a;
        }
        ao.x = aov[0]; ao.y = aov[1]; ao.z = aov[2]; ao.w = aov[3];
        *(float4*)&out[ATTN_OFF + (size_t)nf * DIMv + h * Dv + d0] = ao;

        if (dm == 0) {
#pragma unroll
            for (int r = 0; r < Rv; ++r) {
                out[ESC_OFF + eb + r] = esc[r];
                out[RSC_OFF + eb + r] = rsc[r];
            }
        }
    }
}

extern "C" void kernel_launch(void* const* d_in, const int* in_sizes, int n_in,
                              void* d_out, int out_size, void* d_ws, size_t ws_size,
                              hipStream_t stream) {
    const float* x        = (const float*)d_in[0];
    const float* mask     = (const float*)d_in[1];
    const float* eps      = (const float*)d_in[2];
    const float* qk_w     = (const float*)d_in[3];
    const float* we_p     = (const float*)d_in[4];
    const float* wr_p     = (const float*)d_in[5];
    const float* log_lam  = (const float*)d_in[6];
    const float* m_u      = (const float*)d_in[7];
    const float* s_tri    = (const float*)d_in[8];
    const float* log_ssqrt= (const float*)d_in[9];
    const float* fw_w     = (const float*)d_in[10];
    const float* fw_b     = (const float*)d_in[11];
    float* out = (float*)d_out;

    _Float16* xh  = (_Float16*)d_ws;
    _Float16* qkh = xh + XHALFS;

    convert_fp16<<<dim3(CONV_BLOCKS + 1), 256, 0, stream>>>(x, qk_w, xh, qkh,
                                                            log_lam, m_u, s_tri, log_ssqrt, out);
    svgp_main<<<dim3(2048), 256, 0, stream>>>(xh, qkh, x, mask, eps, we_p, wr_p,
                                              log_lam, m_u, s_tri, log_ssqrt, fw_w, fw_b, out);
}